// Round 3
// baseline (111.947 us; speedup 1.0000x reference)
//
#include <hip/hip_runtime.h>
#include <math.h>

#define TABLE 256
#define DIM   768
#define CAP   512          // bucket capacity per row (real max ~30 for Poisson(8))

__device__ __forceinline__ float4 f4zero() { return make_float4(0.f, 0.f, 0.f, 0.f); }

// ---------------- kernel 1: zero counts + transpose Wrow ----------------
__global__ __launch_bounds__(256) void k_ztrans(
    const float* __restrict__ Wrow,   // (256, 768)
    float* __restrict__ WrowT,        // (768, 256)
    int* __restrict__ counts)         // (256)
{
    const int d = blockIdx.x;
    const int c = threadIdx.x;
    if (d == 0) counts[c] = 0;
    WrowT[(size_t)d * TABLE + c] = Wrow[(size_t)c * DIM + d];
}

// ---------------- kernel 2: bucket tokens by row id ----------------
__global__ __launch_bounds__(256) void k_bucket(
    const int* __restrict__ tgt, int ntok,
    int* __restrict__ counts, int* __restrict__ bucket)
{
    const int n = blockIdx.x * 256 + threadIdx.x;
    if (n >= ntok) return;
    const int r = tgt[n] >> 8;
    const int pos = atomicAdd(&counts[r], 1);
    if (pos < CAP) bucket[r * CAP + pos] = n;
}

// ---------------- 16-token x 32-col GEMM body ----------------
// 256 threads: c4 = tid&7 (8 col-quads = 32 cols), dp = tid>>3 (32-way d-split).
// out[toks[k]][cbase..cbase+31] = hs[toks[k]] . slab[:, cbase..] + bias
__device__ __forceinline__ void gemm_body16(
    const float4* __restrict__ slab4,   // (768, 64) float4 (d-major, 256 cols)
    const float*  __restrict__ hs,      // (NTOK, 768)
    const int* __restrict__ toks_s,     // LDS, 16 valid token indices
    int kmax,
    float (*hs_s)[DIM],                 // LDS [16][768]
    float4 (*red)[8][4],                // LDS [16][8][4] float4
    const float4* __restrict__ bias4,   // (64) float4
    int cbase,
    float* __restrict__ outp,           // (NTOK, 256)
    int tid)
{
    // stage 16 token rows into LDS (12 float4 per thread, coalesced)
    for (int idx = tid; idx < 16 * (DIM / 4); idx += 256) {
        const int k = idx / (DIM / 4);
        const int i = idx - k * (DIM / 4);
        reinterpret_cast<float4*>(hs_s[k])[i] =
            reinterpret_cast<const float4*>(hs + (size_t)toks_s[k] * DIM)[i];
    }
    __syncthreads();

    const int c4 = tid & 7;
    const int dp = tid >> 3;
    const int cq = (cbase >> 2) + c4;

    float4 acc[16];
    #pragma unroll
    for (int k = 0; k < 16; ++k) acc[k] = f4zero();

    #pragma unroll 2
    for (int d = dp; d < DIM; d += 32) {
        const float4 w = slab4[(size_t)d * (TABLE / 4) + cq];
        float h[16];
        #pragma unroll
        for (int k = 0; k < 16; ++k) h[k] = hs_s[k][d];
        #pragma unroll
        for (int k = 0; k < 16; ++k) {
            acc[k].x = fmaf(h[k], w.x, acc[k].x);
            acc[k].y = fmaf(h[k], w.y, acc[k].y);
            acc[k].z = fmaf(h[k], w.z, acc[k].z);
            acc[k].w = fmaf(h[k], w.w, acc[k].w);
        }
    }

    // reduce over dp within wave: lane bits 3,4,5
    #pragma unroll
    for (int k = 0; k < 16; ++k) {
        #pragma unroll
        for (int off = 8; off <= 32; off <<= 1) {
            acc[k].x += __shfl_xor(acc[k].x, off);
            acc[k].y += __shfl_xor(acc[k].y, off);
            acc[k].z += __shfl_xor(acc[k].z, off);
            acc[k].w += __shfl_xor(acc[k].w, off);
        }
    }

    const int lane = tid & 63;
    const int w    = tid >> 6;
    if (lane < 8) {
        #pragma unroll
        for (int k = 0; k < 16; ++k) red[k][lane][w] = acc[k];
    }
    __syncthreads();

    if (tid < 128) {
        const int k = tid >> 3;
        const int q = tid & 7;
        if (k < kmax) {
            const float4 a = red[k][q][0];
            const float4 b = red[k][q][1];
            const float4 c = red[k][q][2];
            const float4 d = red[k][q][3];
            const float4 bi = bias4[(cbase >> 2) + q];
            float4 o;
            o.x = a.x + b.x + c.x + d.x + bi.x;
            o.y = a.y + b.y + c.y + d.y + bi.y;
            o.z = a.z + b.z + c.z + d.z + bi.z;
            o.w = a.w + b.w + c.w + d.w + bi.w;
            reinterpret_cast<float4*>(outp + (size_t)toks_s[k] * TABLE + cbase)[q] = o;
        }
    }
    __syncthreads();
}

// ---------------- kernel 3: both GEMMs ----------------
// blocks [0, 2048): col head — row r = bid>>3, 32-col slice = bid&7
// blocks [2048, 2048 + 8*ntok/16): row head — 16-token tile, 32-col slice
__global__ __launch_bounds__(256) void k_gemms(
    const float* __restrict__ hs,
    const float* __restrict__ WrowT,
    const float* __restrict__ brow,
    const float* __restrict__ CW,
    const float* __restrict__ cbias,
    const int* __restrict__ counts,
    const int* __restrict__ bucket,
    float* __restrict__ row_logits,
    float* __restrict__ col_logits)
{
    __shared__ float  hs_s[16][DIM];
    __shared__ float4 red[16][8][4];
    __shared__ int    toks_s[16];

    const int bid = blockIdx.x;
    const int tid = threadIdx.x;

    if (bid < 2048) {
        const int r = bid >> 3;
        const int cbase = (bid & 7) * 32;
        const int cnt = min(counts[r], CAP);
        if (cnt == 0) return;
        const float4* slab4 = reinterpret_cast<const float4*>(CW + (size_t)r * DIM * TABLE);
        const float4* bias4 = reinterpret_cast<const float4*>(cbias + (size_t)r * TABLE);
        for (int base = 0; base < cnt; base += 16) {
            const int kmax = min(16, cnt - base);
            if (tid < 16)
                toks_s[tid] = (tid < kmax) ? bucket[r * CAP + base + tid]
                                           : bucket[r * CAP + base];
            __syncthreads();
            gemm_body16(slab4, hs, toks_s, kmax, hs_s, red, bias4, cbase, col_logits, tid);
        }
    } else {
        const int b = bid - 2048;
        const int tile = b >> 3;
        const int cbase = (b & 7) * 32;
        if (tid < 16) toks_s[tid] = tile * 16 + tid;
        __syncthreads();
        gemm_body16(reinterpret_cast<const float4*>(WrowT), hs, toks_s, 16,
                    hs_s, red, reinterpret_cast<const float4*>(brow),
                    cbase, row_logits, tid);
    }
}

// ---------------- kernel 4: wave-parallel NLL per token ----------------
__device__ __forceinline__ float wave_nll(float4 v, int target, int lane) {
    float m = fmaxf(fmaxf(v.x, v.y), fmaxf(v.z, v.w));
    #pragma unroll
    for (int off = 32; off > 0; off >>= 1) m = fmaxf(m, __shfl_xor(m, off));
    float e = expf(v.x - m) + expf(v.y - m) + expf(v.z - m) + expf(v.w - m);
    float lt = 0.f;
    if (lane == (target >> 2)) {
        const int j = target & 3;
        lt = (j == 0) ? v.x : (j == 1) ? v.y : (j == 2) ? v.z : v.w;
    }
    #pragma unroll
    for (int off = 32; off > 0; off >>= 1) {
        e  += __shfl_xor(e, off);
        lt += __shfl_xor(lt, off);
    }
    return m + logf(e) - lt;
}

__global__ __launch_bounds__(256) void k_nll(
    const float* __restrict__ row_logits,
    const float* __restrict__ col_logits,
    const int* __restrict__ tgt, int ntok,
    float* __restrict__ per_tok)
{
    const int n = blockIdx.x * 4 + (threadIdx.x >> 6);
    if (n >= ntok) return;
    const int lane = threadIdx.x & 63;
    const int t = tgt[n];
    const float4 rl = reinterpret_cast<const float4*>(row_logits + (size_t)n * TABLE)[lane];
    const float4 cl = reinterpret_cast<const float4*>(col_logits + (size_t)n * TABLE)[lane];
    const float lr = wave_nll(rl, t >> 8, lane);
    const float lc = wave_nll(cl, t & 255, lane);
    if (lane == 0) per_tok[n] = lr + lc;
}

// ---------------- kernel 5: mean reduce ----------------
__global__ __launch_bounds__(256) void k_reduce(
    const float* __restrict__ per_tok, int ntok, float* __restrict__ out)
{
    __shared__ float red[256];
    const int c = threadIdx.x;
    float s = 0.f;
    for (int i = c; i < ntok; i += 256) s += per_tok[i];
    red[c] = s;
    __syncthreads();
    #pragma unroll
    for (int k = 128; k > 0; k >>= 1) {
        if (c < k) red[c] += red[c + k];
        __syncthreads();
    }
    if (c == 0) out[0] = red[0] / (float)ntok;
}

extern "C" void kernel_launch(void* const* d_in, const int* in_sizes, int n_in,
                              void* d_out, int out_size, void* d_ws, size_t ws_size,
                              hipStream_t stream) {
    const float* hs    = (const float*)d_in[0];
    const int*   tgt   = (const int*)d_in[1];
    const float* Wrow  = (const float*)d_in[2];
    const float* brow  = (const float*)d_in[3];
    const float* CW    = (const float*)d_in[4];
    const float* cbias = (const float*)d_in[5];
    float* out = (float*)d_out;

    const int ntok = in_sizes[1];   // 2048

    // workspace layout
    char* ws = (char*)d_ws;
    int*   counts     = (int*)(ws);                               // 1 KB
    int*   bucket     = (int*)(ws + 1024);                        // 512 KB
    float* WrowT      = (float*)(ws + 1024 + 256 * CAP * 4);      // 768 KB
    float* row_logits = (float*)((char*)WrowT + DIM * TABLE * 4); // 2 MB
    float* col_logits = row_logits + (size_t)ntok * TABLE;        // 2 MB
    float* per_tok    = col_logits + (size_t)ntok * TABLE;        // 8 KB

    k_ztrans <<<DIM, 256, 0, stream>>>(Wrow, WrowT, counts);
    k_bucket <<<(ntok + 255) / 256, 256, 0, stream>>>(tgt, ntok, counts, bucket);
    const int row_blocks = 8 * (ntok / 16);
    k_gemms  <<<2048 + row_blocks, 256, 0, stream>>>(hs, WrowT, brow, CW, cbias,
                                                     counts, bucket, row_logits, col_logits);
    k_nll    <<<(ntok + 3) / 4, 256, 0, stream>>>(row_logits, col_logits, tgt, ntok, per_tok);
    k_reduce <<<1, 256, 0, stream>>>(per_tok, ntok, out);
}

// Round 7
// 92.655 us; speedup vs baseline: 1.2082x; 1.2082x over previous
//
#include <hip/hip_runtime.h>
#include <math.h>

#define TABLE 256
#define DIM   768
#define NCH   6
#define DCH   128          // DIM / NCH
#define CAP   512          // bucket capacity per row (real max ~30 for Poisson(8))

__device__ __forceinline__ float4 f4zero() { return make_float4(0.f, 0.f, 0.f, 0.f); }

// ---------------- kernel 1: zero counts + transpose Wrow ----------------
__global__ __launch_bounds__(256) void k_ztrans(
    const float* __restrict__ Wrow,   // (256, 768)
    float* __restrict__ WrowT,        // (768, 256)
    int* __restrict__ counts)         // (256)
{
    const int d = blockIdx.x;
    const int c = threadIdx.x;
    if (d == 0) counts[c] = 0;
    WrowT[(size_t)d * TABLE + c] = Wrow[(size_t)c * DIM + d];
}

// ---------------- kernel 2: bucket tokens by row id ----------------
__global__ __launch_bounds__(256) void k_bucket(
    const int* __restrict__ tgt, int ntok,
    int* __restrict__ counts, int* __restrict__ bucket)
{
    const int n = blockIdx.x * 256 + threadIdx.x;
    if (n >= ntok) return;
    const int r = tgt[n] >> 8;
    const int pos = atomicAdd(&counts[r], 1);
    if (pos < CAP) bucket[r * CAP + pos] = n;
}

// ---------------- d-chunk partial GEMM body ----------------
// 256 threads, 4 waves. Wave w owns col-quads cq = w*16 + (lane&15) (64 cols per
// wave, 256 per block); dsub = lane>>4 splits the d-chunk 4 ways. Loads are
// 256B-contiguous float4 streams; h is a wave-broadcast LDS read; dsub-reduce
// is in-wave shfl_xor. No LDS tree, no barrier in the hot loop.
template<int K>
__device__ __forceinline__ void partial_body(
    const float4* __restrict__ slab4,   // chunk base: (DCH, 64) float4
    const float*  __restrict__ hs,      // (ntok, 768)
    const int* __restrict__ toks_s,     // 16 entries, -1 = invalid
    float (*hs_s)[DCH],
    int chunk,
    float* __restrict__ outp,           // partial[chunk] base: (ntok, 256)
    int tid)
{
    // stage hs chunk rows: 16 tokens x 128 floats (8 KB), zero-fill invalid
    for (int idx = tid; idx < 16 * (DCH / 4); idx += 256) {
        const int k = idx >> 5;          // DCH/4 = 32 quads per token
        const int i = idx & 31;
        const int n = toks_s[k];
        float4 v = f4zero();
        if (k < K && n >= 0)
            v = reinterpret_cast<const float4*>(hs + (size_t)n * DIM + chunk * DCH)[i];
        reinterpret_cast<float4*>(hs_s[k])[i] = v;
    }
    __syncthreads();

    const int lane = tid & 63;
    const int w    = tid >> 6;
    const int cq   = (w << 4) | (lane & 15);
    const int dsub = lane >> 4;

    float4 acc[K];
    #pragma unroll
    for (int k = 0; k < K; ++k) acc[k] = f4zero();

    #pragma unroll 8
    for (int i = 0; i < DCH / 4; ++i) {
        const int d = dsub + (i << 2);
        const float4 wv = slab4[(size_t)d * (TABLE / 4) + cq];
        #pragma unroll
        for (int k = 0; k < K; ++k) {
            const float h = hs_s[k][d];
            acc[k].x = fmaf(h, wv.x, acc[k].x);
            acc[k].y = fmaf(h, wv.y, acc[k].y);
            acc[k].z = fmaf(h, wv.z, acc[k].z);
            acc[k].w = fmaf(h, wv.w, acc[k].w);
        }
    }

    // reduce over dsub (lane bits 4,5) — in-wave
    #pragma unroll
    for (int k = 0; k < K; ++k) {
        #pragma unroll
        for (int off = 16; off <= 32; off <<= 1) {
            acc[k].x += __shfl_xor(acc[k].x, off);
            acc[k].y += __shfl_xor(acc[k].y, off);
            acc[k].z += __shfl_xor(acc[k].z, off);
            acc[k].w += __shfl_xor(acc[k].w, off);
        }
    }

    if (lane < 16) {
        #pragma unroll
        for (int k = 0; k < K; ++k) {
            const int n = toks_s[k];
            if (n >= 0)
                reinterpret_cast<float4*>(outp + (size_t)n * TABLE)[cq] = acc[k];
        }
    }
    __syncthreads();   // protect toks_s/hs_s for a following base-iteration
}

// ---------------- kernel 3: partial GEMMs (col + row heads) ----------------
// blocks [0, 1536): col head — r = bid&255, chunk = bid>>8
// blocks [1536, 2304): row head — tile = b&127, chunk = b>>7 (WrowT as slab)
__global__ __launch_bounds__(256) void k_partial(
    const float* __restrict__ hs,
    const float* __restrict__ WrowT,
    const float* __restrict__ CW,
    const int* __restrict__ counts,
    const int* __restrict__ bucket,
    float* __restrict__ row_part,       // (NCH, ntok, 256)
    float* __restrict__ col_part,       // (NCH, ntok, 256)
    int ntok)
{
    __shared__ float hs_s[16][DCH];
    __shared__ int   toks_s[16];

    const int bid = blockIdx.x;
    const int tid = threadIdx.x;
    const int ncol = 256 * NCH;         // 1536

    if (bid < ncol) {
        const int r     = bid & 255;
        const int chunk = bid >> 8;     // 0..5
        const int cnt = min(counts[r], CAP);
        if (cnt == 0) return;
        const float4* slab4 = reinterpret_cast<const float4*>(
            CW + (size_t)r * DIM * TABLE + (size_t)chunk * DCH * TABLE);
        float* outp = col_part + (size_t)chunk * ntok * TABLE;
        for (int base = 0; base < cnt; base += 16) {
            if (tid < 16)
                toks_s[tid] = (base + tid < cnt) ? bucket[r * CAP + base + tid] : -1;
            __syncthreads();
            const int kmax = cnt - base;
            if (kmax <= 8) partial_body<8>(slab4, hs, toks_s, hs_s, chunk, outp, tid);
            else           partial_body<16>(slab4, hs, toks_s, hs_s, chunk, outp, tid);
        }
    } else {
        const int b     = bid - ncol;   // 0..767
        const int tile  = b & 127;
        const int chunk = b >> 7;       // 0..5
        if (tid < 16) toks_s[tid] = tile * 16 + tid;
        __syncthreads();
        const float4* slab4 = reinterpret_cast<const float4*>(
            WrowT + (size_t)chunk * DCH * TABLE);
        float* outp = row_part + (size_t)chunk * ntok * TABLE;
        partial_body<16>(slab4, hs, toks_s, hs_s, chunk, outp, tid);
    }
}

// ---------------- kernel 4: fused partial-sum + bias + NLL ----------------
__device__ __forceinline__ float wave_nll(float4 v, int target, int lane) {
    float m = fmaxf(fmaxf(v.x, v.y), fmaxf(v.z, v.w));
    #pragma unroll
    for (int off = 32; off > 0; off >>= 1) m = fmaxf(m, __shfl_xor(m, off));
    float e = expf(v.x - m) + expf(v.y - m) + expf(v.z - m) + expf(v.w - m);
    float lt = 0.f;
    if (lane == (target >> 2)) {
        const int j = target & 3;
        lt = (j == 0) ? v.x : (j == 1) ? v.y : (j == 2) ? v.z : v.w;
    }
    #pragma unroll
    for (int off = 32; off > 0; off >>= 1) {
        e  += __shfl_xor(e, off);
        lt += __shfl_xor(lt, off);
    }
    return m + logf(e) - lt;
}

__global__ __launch_bounds__(256) void k_nll2(
    const float* __restrict__ row_part,
    const float* __restrict__ col_part,
    const float* __restrict__ brow,
    const float* __restrict__ cbias,
    const int* __restrict__ tgt, int ntok,
    float* __restrict__ per_tok)
{
    const int n = blockIdx.x * 4 + (threadIdx.x >> 6);
    if (n >= ntok) return;
    const int lane = threadIdx.x & 63;
    const int t = tgt[n];
    const int r = t >> 8;

    float4 rl = reinterpret_cast<const float4*>(brow)[lane];
    float4 cl = reinterpret_cast<const float4*>(cbias + (size_t)r * TABLE)[lane];
    #pragma unroll
    for (int ch = 0; ch < NCH; ++ch) {
        const float4 a = reinterpret_cast<const float4*>(
            row_part + ((size_t)ch * ntok + n) * TABLE)[lane];
        const float4 b = reinterpret_cast<const float4*>(
            col_part + ((size_t)ch * ntok + n) * TABLE)[lane];
        rl.x += a.x; rl.y += a.y; rl.z += a.z; rl.w += a.w;
        cl.x += b.x; cl.y += b.y; cl.z += b.z; cl.w += b.w;
    }
    const float lr = wave_nll(rl, r, lane);
    const float lc = wave_nll(cl, t & 255, lane);
    if (lane == 0) per_tok[n] = lr + lc;
}

// ---------------- kernel 5: mean reduce ----------------
__global__ __launch_bounds__(256) void k_reduce(
    const float* __restrict__ per_tok, int ntok, float* __restrict__ out)
{
    __shared__ float red[256];
    const int c = threadIdx.x;
    float s = 0.f;
    for (int i = c; i < ntok; i += 256) s += per_tok[i];
    red[c] = s;
    __syncthreads();
    #pragma unroll
    for (int k = 128; k > 0; k >>= 1) {
        if (c < k) red[c] += red[c + k];
        __syncthreads();
    }
    if (c == 0) out[0] = red[0] / (float)ntok;
}

extern "C" void kernel_launch(void* const* d_in, const int* in_sizes, int n_in,
                              void* d_out, int out_size, void* d_ws, size_t ws_size,
                              hipStream_t stream) {
    const float* hs    = (const float*)d_in[0];
    const int*   tgt   = (const int*)d_in[1];
    const float* Wrow  = (const float*)d_in[2];
    const float* brow  = (const float*)d_in[3];
    const float* CW    = (const float*)d_in[4];
    const float* cbias = (const float*)d_in[5];
    float* out = (float*)d_out;

    const int ntok = in_sizes[1];   // 2048

    // workspace layout (bytes)
    char* ws = (char*)d_ws;
    int*   counts   = (int*)(ws);                                  // 1 KB
    int*   bucket   = (int*)(ws + 1024);                           // 512 KB
    float* WrowT    = (float*)(ws + 1024 + 256 * CAP * 4);         // 768 KB
    char*  p0       = (char*)WrowT + (size_t)DIM * TABLE * 4;
    float* row_part = (float*)p0;                                  // 12.6 MB
    float* col_part = row_part + (size_t)NCH * ntok * TABLE;       // 12.6 MB
    float* per_tok  = col_part + (size_t)NCH * ntok * TABLE;       // 8 KB

    k_ztrans <<<DIM, 256, 0, stream>>>(Wrow, WrowT, counts);
    k_bucket <<<(ntok + 255) / 256, 256, 0, stream>>>(tgt, ntok, counts, bucket);
    const int nblk = 256 * NCH + (ntok / 16) * NCH;   // 1536 + 768
    k_partial<<<nblk, 256, 0, stream>>>(hs, WrowT, CW, counts, bucket,
                                        row_part, col_part, ntok);
    k_nll2   <<<(ntok + 3) / 4, 256, 0, stream>>>(row_part, col_part, brow, cbias,
                                                  tgt, ntok, per_tok);
    k_reduce <<<1, 256, 0, stream>>>(per_tok, ntok, out);
}

// Round 8
// 82.073 us; speedup vs baseline: 1.3640x; 1.1289x over previous
//
#include <hip/hip_runtime.h>
#include <math.h>

#define TABLE 256
#define DIM   768
#define NCH   6
#define DCH   128          // DIM / NCH
#define KTOK  12           // tokens per pass (acc = 48 VGPR)
#define CAP   64           // bucket capacity (P(cnt>64) ~ 0 for Poisson(8))

__device__ __forceinline__ float4 f4zero() { return make_float4(0.f, 0.f, 0.f, 0.f); }

// ---------------- kernel 1: zero counts + transpose Wrow ----------------
__global__ __launch_bounds__(256) void k_ztrans(
    const float* __restrict__ Wrow,   // (256, 768)
    float* __restrict__ WrowT,        // (768, 256)
    int* __restrict__ counts)         // (256)
{
    const int d = blockIdx.x;
    const int c = threadIdx.x;
    if (d == 0) counts[c] = 0;
    WrowT[(size_t)d * TABLE + c] = Wrow[(size_t)c * DIM + d];
}

// ---------------- kernel 2: bucket tokens by row id ----------------
__global__ __launch_bounds__(256) void k_bucket(
    const int* __restrict__ tgt, int ntok,
    int* __restrict__ counts, int* __restrict__ bucket)
{
    const int n = blockIdx.x * 256 + threadIdx.x;
    if (n >= ntok) return;
    const int r = tgt[n] >> 8;
    const int pos = atomicAdd(&counts[r], 1);
    if (pos < CAP) bucket[r * CAP + pos] = n;
}

// ---------------- one streaming pass: 12 tokens x 256 cols x DCH d ----------------
// Single wave. lane = col-quad (4 cols). tk[] wave-uniform (SGPR). h-tiles are
// uniform float4 loads -> s_load_dwordx4 (SGPRs). The ONLY vector stream is the
// slab: sequential 1KB lines. acc[12] float4 = 48 VGPR. No LDS, no barriers.
__device__ __forceinline__ void stream_pass(
    const float4* __restrict__ slab4,   // (DCH, 64) float4: d-major, 256 cols
    const float*  __restrict__ hs,      // (ntok, 768)
    const int* tk,                      // KTOK uniform token ids (clamped valid)
    int nvalid,                         // how many of tk to store
    int dbase,                          // chunk * DCH
    float* __restrict__ outp,           // partial base (ntok, 256)
    int lane)
{
    int off[KTOK];
    #pragma unroll
    for (int j = 0; j < KTOK; ++j) off[j] = tk[j] * DIM + dbase;

    float4 acc[KTOK];
    #pragma unroll
    for (int j = 0; j < KTOK; ++j) acc[j] = f4zero();

    for (int dq = 0; dq < DCH / 4; ++dq) {
        float4 hv[KTOK];                 // uniform -> scalar regs
        #pragma unroll
        for (int j = 0; j < KTOK; ++j)
            hv[j] = reinterpret_cast<const float4*>(hs + off[j])[dq];
        #pragma unroll
        for (int dd = 0; dd < 4; ++dd) {
            const float4 wv = slab4[(size_t)(dq * 4 + dd) * 64 + lane];
            #pragma unroll
            for (int j = 0; j < KTOK; ++j) {
                const float h = (dd == 0) ? hv[j].x : (dd == 1) ? hv[j].y
                              : (dd == 2) ? hv[j].z : hv[j].w;
                acc[j].x = fmaf(h, wv.x, acc[j].x);
                acc[j].y = fmaf(h, wv.y, acc[j].y);
                acc[j].z = fmaf(h, wv.z, acc[j].z);
                acc[j].w = fmaf(h, wv.w, acc[j].w);
            }
        }
    }

    #pragma unroll
    for (int j = 0; j < KTOK; ++j)
        if (j < nvalid)
            reinterpret_cast<float4*>(outp + (size_t)tk[j] * TABLE)[lane] = acc[j];
}

// ---------------- kernel 3: streaming partial GEMMs ----------------
// blocks [0, 1536): col head — r = bid&255, chunk = bid>>8
// blocks [1536, ...): row head — b = bid-1536, tile = b%ntiles, chunk = b/ntiles
__global__ __launch_bounds__(64) void k_stream(
    const float* __restrict__ hs,
    const float* __restrict__ WrowT,
    const float* __restrict__ CW,
    const int* __restrict__ counts,
    const int* __restrict__ bucket,
    float* __restrict__ row_part,       // (NCH, ntok, 256)
    float* __restrict__ col_part,       // (NCH, ntok, 256)
    int ntok)
{
    const int bid  = blockIdx.x;
    const int lane = threadIdx.x;
    const int ncol = 256 * NCH;         // 1536
    int tk[KTOK];

    if (bid < ncol) {
        const int r     = bid & 255;
        const int chunk = bid >> 8;     // 0..5
        const int cnt = min(counts[r], CAP);
        if (cnt == 0) return;
        const float4* slab4 = reinterpret_cast<const float4*>(
            CW + (size_t)r * DIM * TABLE + (size_t)chunk * DCH * TABLE);
        float* outp = col_part + (size_t)chunk * ntok * TABLE;
        for (int base = 0; base < cnt; base += KTOK) {
            #pragma unroll
            for (int j = 0; j < KTOK; ++j) {
                const int idx = (base + j < cnt) ? (base + j) : base;
                tk[j] = __builtin_amdgcn_readfirstlane(bucket[r * CAP + idx]);
            }
            stream_pass(slab4, hs, tk, min(KTOK, cnt - base),
                        chunk * DCH, outp, lane);
        }
    } else {
        const int b      = bid - ncol;
        const int ntiles = (ntok + KTOK - 1) / KTOK;   // 171
        const int tile   = b % ntiles;
        const int chunk  = b / ntiles;  // 0..5
        const int cnt    = min(KTOK, ntok - tile * KTOK);
        #pragma unroll
        for (int j = 0; j < KTOK; ++j) {
            const int idx = (j < cnt) ? j : 0;
            tk[j] = tile * KTOK + idx;
        }
        const float4* slab4 = reinterpret_cast<const float4*>(
            WrowT + (size_t)chunk * DCH * TABLE);
        float* outp = row_part + (size_t)chunk * ntok * TABLE;
        stream_pass(slab4, hs, tk, cnt, chunk * DCH, outp, lane);
    }
}

// ---------------- kernel 4: fused partial-sum + bias + NLL ----------------
__device__ __forceinline__ float wave_nll(float4 v, int target, int lane) {
    float m = fmaxf(fmaxf(v.x, v.y), fmaxf(v.z, v.w));
    #pragma unroll
    for (int off = 32; off > 0; off >>= 1) m = fmaxf(m, __shfl_xor(m, off));
    float e = expf(v.x - m) + expf(v.y - m) + expf(v.z - m) + expf(v.w - m);
    float lt = 0.f;
    if (lane == (target >> 2)) {
        const int j = target & 3;
        lt = (j == 0) ? v.x : (j == 1) ? v.y : (j == 2) ? v.z : v.w;
    }
    #pragma unroll
    for (int off = 32; off > 0; off >>= 1) {
        e  += __shfl_xor(e, off);
        lt += __shfl_xor(lt, off);
    }
    return m + logf(e) - lt;
}

__global__ __launch_bounds__(256) void k_nll2(
    const float* __restrict__ row_part,
    const float* __restrict__ col_part,
    const float* __restrict__ brow,
    const float* __restrict__ cbias,
    const int* __restrict__ tgt, int ntok,
    float* __restrict__ per_tok)
{
    const int n = blockIdx.x * 4 + (threadIdx.x >> 6);
    if (n >= ntok) return;
    const int lane = threadIdx.x & 63;
    const int t = tgt[n];
    const int r = t >> 8;

    float4 rl = reinterpret_cast<const float4*>(brow)[lane];
    float4 cl = reinterpret_cast<const float4*>(cbias + (size_t)r * TABLE)[lane];
    #pragma unroll
    for (int ch = 0; ch < NCH; ++ch) {
        const float4 a = reinterpret_cast<const float4*>(
            row_part + ((size_t)ch * ntok + n) * TABLE)[lane];
        const float4 b = reinterpret_cast<const float4*>(
            col_part + ((size_t)ch * ntok + n) * TABLE)[lane];
        rl.x += a.x; rl.y += a.y; rl.z += a.z; rl.w += a.w;
        cl.x += b.x; cl.y += b.y; cl.z += b.z; cl.w += b.w;
    }
    const float lr = wave_nll(rl, r, lane);
    const float lc = wave_nll(cl, t & 255, lane);
    if (lane == 0) per_tok[n] = lr + lc;
}

// ---------------- kernel 5: mean reduce ----------------
__global__ __launch_bounds__(256) void k_reduce(
    const float* __restrict__ per_tok, int ntok, float* __restrict__ out)
{
    __shared__ float red[256];
    const int c = threadIdx.x;
    float s = 0.f;
    for (int i = c; i < ntok; i += 256) s += per_tok[i];
    red[c] = s;
    __syncthreads();
    #pragma unroll
    for (int k = 128; k > 0; k >>= 1) {
        if (c < k) red[c] += red[c + k];
        __syncthreads();
    }
    if (c == 0) out[0] = red[0] / (float)ntok;
}

extern "C" void kernel_launch(void* const* d_in, const int* in_sizes, int n_in,
                              void* d_out, int out_size, void* d_ws, size_t ws_size,
                              hipStream_t stream) {
    const float* hs    = (const float*)d_in[0];
    const int*   tgt   = (const int*)d_in[1];
    const float* Wrow  = (const float*)d_in[2];
    const float* brow  = (const float*)d_in[3];
    const float* CW    = (const float*)d_in[4];
    const float* cbias = (const float*)d_in[5];
    float* out = (float*)d_out;

    const int ntok = in_sizes[1];   // 2048

    // workspace layout (bytes) — ~26.2 MB total (same footprint as proven R4)
    char* ws = (char*)d_ws;
    int*   counts   = (int*)(ws);                                  // 1 KB
    int*   bucket   = (int*)(ws + 1024);                           // 64 KB
    float* WrowT    = (float*)(ws + 1024 + 256 * CAP * 4);         // 768 KB
    char*  p0       = (char*)WrowT + (size_t)DIM * TABLE * 4;
    float* row_part = (float*)p0;                                  // 12.6 MB
    float* col_part = row_part + (size_t)NCH * ntok * TABLE;       // 12.6 MB
    float* per_tok  = col_part + (size_t)NCH * ntok * TABLE;       // 8 KB

    const int ntiles = (ntok + KTOK - 1) / KTOK;   // 171
    const int nblk   = 256 * NCH + ntiles * NCH;   // 1536 + 1026 = 2562

    k_ztrans <<<DIM, 256, 0, stream>>>(Wrow, WrowT, counts);
    k_bucket <<<(ntok + 255) / 256, 256, 0, stream>>>(tgt, ntok, counts, bucket);
    k_stream <<<nblk, 64, 0, stream>>>(hs, WrowT, CW, counts, bucket,
                                       row_part, col_part, ntok);
    k_nll2   <<<(ntok + 3) / 4, 256, 0, stream>>>(row_part, col_part, brow, cbias,
                                                  tgt, ntok, per_tok);
    k_reduce <<<1, 256, 0, stream>>>(per_tok, ntok, out);
}

// Round 9
// 76.270 us; speedup vs baseline: 1.4678x; 1.0761x over previous
//
#include <hip/hip_runtime.h>
#include <math.h>

#define TABLE 256
#define DIM   768
#define NCH   6
#define DCH   128          // DIM / NCH
#define KTOK  12           // tokens per pass (acc = 24 VGPR as float2)
#define CAP   64           // bucket capacity (P(cnt>64) ~ 0 for Poisson(8))

__device__ __forceinline__ float2 f2zero() { return make_float2(0.f, 0.f); }

// ---------------- kernel 1: zero counts + transpose Wrow ----------------
__global__ __launch_bounds__(256) void k_ztrans(
    const float* __restrict__ Wrow,   // (256, 768)
    float* __restrict__ WrowT,        // (768, 256)
    int* __restrict__ counts)         // (256)
{
    const int d = blockIdx.x;
    const int c = threadIdx.x;
    if (d == 0) counts[c] = 0;
    WrowT[(size_t)d * TABLE + c] = Wrow[(size_t)c * DIM + d];
}

// ---------------- kernel 2: bucket tokens by row id ----------------
__global__ __launch_bounds__(256) void k_bucket(
    const int* __restrict__ tgt, int ntok,
    int* __restrict__ counts, int* __restrict__ bucket)
{
    const int n = blockIdx.x * 256 + threadIdx.x;
    if (n >= ntok) return;
    const int r = tgt[n] >> 8;
    const int pos = atomicAdd(&counts[r], 1);
    if (pos < CAP) bucket[r * CAP + pos] = n;
}

// ---------------- one streaming pass: 12 tokens x 128 cols x DCH d ----------------
// Single wave, half the columns (cbase = 0 or 128). lane = col-pair (float2).
// tk[] wave-uniform. Slab reads: 512B contiguous per d. acc[12] float2 = 24 VGPR.
// No LDS, no barriers, reduction-free (each lane owns its 2 cols end-to-end).
__device__ __forceinline__ void stream_pass(
    const float* __restrict__ slab,     // chunk base: (DCH, 256) floats
    const float* __restrict__ hs,       // (ntok, 768)
    const int* tk,                      // KTOK uniform token ids (clamped valid)
    int nvalid,
    int dbase,                          // chunk * DCH
    int cbase,                          // 0 or 128
    float* __restrict__ outp,           // partial base (ntok, 256)
    int lane)
{
    int off[KTOK];
    #pragma unroll
    for (int j = 0; j < KTOK; ++j) off[j] = tk[j] * DIM + dbase;

    float2 acc[KTOK];
    #pragma unroll
    for (int j = 0; j < KTOK; ++j) acc[j] = f2zero();

    const float* sl = slab + cbase + 2 * lane;

    #pragma unroll 2
    for (int dq = 0; dq < DCH / 4; ++dq) {
        float4 hv[KTOK];                 // uniform loads
        #pragma unroll
        for (int j = 0; j < KTOK; ++j)
            hv[j] = reinterpret_cast<const float4*>(hs + off[j])[dq];
        #pragma unroll
        for (int dd = 0; dd < 4; ++dd) {
            const float2 wv = *reinterpret_cast<const float2*>(
                sl + (size_t)(dq * 4 + dd) * TABLE);
            #pragma unroll
            for (int j = 0; j < KTOK; ++j) {
                const float h = (dd == 0) ? hv[j].x : (dd == 1) ? hv[j].y
                              : (dd == 2) ? hv[j].z : hv[j].w;
                acc[j].x = fmaf(h, wv.x, acc[j].x);
                acc[j].y = fmaf(h, wv.y, acc[j].y);
            }
        }
    }

    #pragma unroll
    for (int j = 0; j < KTOK; ++j)
        if (j < nvalid)
            *reinterpret_cast<float2*>(outp + (size_t)tk[j] * TABLE + cbase + 2 * lane)
                = acc[j];
}

// ---------------- kernel 3: streaming partial GEMMs ----------------
// blocks [0, 3072): col head — r = bid&255, rest = bid>>8: chunk = rest>>1, chalf = rest&1
// blocks [3072, ..): row head — b % ntiles = tile, rest = b/ntiles: chunk/chalf as above
__global__ __launch_bounds__(64) void k_stream(
    const float* __restrict__ hs,
    const float* __restrict__ WrowT,
    const float* __restrict__ CW,
    const int* __restrict__ counts,
    const int* __restrict__ bucket,
    float* __restrict__ row_part,       // (NCH, ntok, 256)
    float* __restrict__ col_part,       // (NCH, ntok, 256)
    int ntok)
{
    const int bid  = blockIdx.x;
    const int lane = threadIdx.x;
    const int ncol = 256 * NCH * 2;     // 3072
    int tk[KTOK];

    if (bid < ncol) {
        const int r     = bid & 255;
        const int rest  = bid >> 8;     // 0..11
        const int chunk = rest >> 1;    // 0..5
        const int cbase = (rest & 1) * 128;
        const int cnt = min(counts[r], CAP);
        if (cnt == 0) return;
        const float* slab = CW + (size_t)r * DIM * TABLE + (size_t)chunk * DCH * TABLE;
        float* outp = col_part + (size_t)chunk * ntok * TABLE;
        for (int base = 0; base < cnt; base += KTOK) {
            #pragma unroll
            for (int j = 0; j < KTOK; ++j) {
                const int idx = (base + j < cnt) ? (base + j) : base;
                tk[j] = __builtin_amdgcn_readfirstlane(bucket[r * CAP + idx]);
            }
            stream_pass(slab, hs, tk, min(KTOK, cnt - base),
                        chunk * DCH, cbase, outp, lane);
        }
    } else {
        const int b      = bid - ncol;
        const int ntiles = (ntok + KTOK - 1) / KTOK;   // 171
        const int tile   = b % ntiles;
        const int rest   = b / ntiles;  // 0..11
        const int chunk  = rest >> 1;
        const int cbase  = (rest & 1) * 128;
        const int cnt    = min(KTOK, ntok - tile * KTOK);
        #pragma unroll
        for (int j = 0; j < KTOK; ++j) {
            const int idx = (j < cnt) ? j : 0;
            tk[j] = tile * KTOK + idx;
        }
        const float* slab = WrowT + (size_t)chunk * DCH * TABLE;
        float* outp = row_part + (size_t)chunk * ntok * TABLE;
        stream_pass(slab, hs, tk, cnt, chunk * DCH, cbase, outp, lane);
    }
}

// ---------------- kernel 4: fused partial-sum + bias + NLL ----------------
__device__ __forceinline__ float wave_nll(float4 v, int target, int lane) {
    float m = fmaxf(fmaxf(v.x, v.y), fmaxf(v.z, v.w));
    #pragma unroll
    for (int off = 32; off > 0; off >>= 1) m = fmaxf(m, __shfl_xor(m, off));
    float e = expf(v.x - m) + expf(v.y - m) + expf(v.z - m) + expf(v.w - m);
    float lt = 0.f;
    if (lane == (target >> 2)) {
        const int j = target & 3;
        lt = (j == 0) ? v.x : (j == 1) ? v.y : (j == 2) ? v.z : v.w;
    }
    #pragma unroll
    for (int off = 32; off > 0; off >>= 1) {
        e  += __shfl_xor(e, off);
        lt += __shfl_xor(lt, off);
    }
    return m + logf(e) - lt;
}

__global__ __launch_bounds__(256) void k_nll2(
    const float* __restrict__ row_part,
    const float* __restrict__ col_part,
    const float* __restrict__ brow,
    const float* __restrict__ cbias,
    const int* __restrict__ tgt, int ntok,
    float* __restrict__ per_tok)
{
    const int n = blockIdx.x * 4 + (threadIdx.x >> 6);
    if (n >= ntok) return;
    const int lane = threadIdx.x & 63;
    const int t = tgt[n];
    const int r = t >> 8;

    float4 rl = reinterpret_cast<const float4*>(brow)[lane];
    float4 cl = reinterpret_cast<const float4*>(cbias + (size_t)r * TABLE)[lane];
    #pragma unroll
    for (int ch = 0; ch < NCH; ++ch) {
        const float4 a = reinterpret_cast<const float4*>(
            row_part + ((size_t)ch * ntok + n) * TABLE)[lane];
        const float4 b = reinterpret_cast<const float4*>(
            col_part + ((size_t)ch * ntok + n) * TABLE)[lane];
        rl.x += a.x; rl.y += a.y; rl.z += a.z; rl.w += a.w;
        cl.x += b.x; cl.y += b.y; cl.z += b.z; cl.w += b.w;
    }
    const float lr = wave_nll(rl, r, lane);
    const float lc = wave_nll(cl, t & 255, lane);
    if (lane == 0) per_tok[n] = lr + lc;
}

// ---------------- kernel 5: mean reduce ----------------
__global__ __launch_bounds__(256) void k_reduce(
    const float* __restrict__ per_tok, int ntok, float* __restrict__ out)
{
    __shared__ float red[256];
    const int c = threadIdx.x;
    float s = 0.f;
    for (int i = c; i < ntok; i += 256) s += per_tok[i];
    red[c] = s;
    __syncthreads();
    #pragma unroll
    for (int k = 128; k > 0; k >>= 1) {
        if (c < k) red[c] += red[c + k];
        __syncthreads();
    }
    if (c == 0) out[0] = red[0] / (float)ntok;
}

extern "C" void kernel_launch(void* const* d_in, const int* in_sizes, int n_in,
                              void* d_out, int out_size, void* d_ws, size_t ws_size,
                              hipStream_t stream) {
    const float* hs    = (const float*)d_in[0];
    const int*   tgt   = (const int*)d_in[1];
    const float* Wrow  = (const float*)d_in[2];
    const float* brow  = (const float*)d_in[3];
    const float* CW    = (const float*)d_in[4];
    const float* cbias = (const float*)d_in[5];
    float* out = (float*)d_out;

    const int ntok = in_sizes[1];   // 2048

    // workspace layout (bytes) — ~26.2 MB total
    char* ws = (char*)d_ws;
    int*   counts   = (int*)(ws);                                  // 1 KB
    int*   bucket   = (int*)(ws + 1024);                           // 64 KB
    float* WrowT    = (float*)(ws + 1024 + 256 * CAP * 4);         // 768 KB
    char*  p0       = (char*)WrowT + (size_t)DIM * TABLE * 4;
    float* row_part = (float*)p0;                                  // 12.6 MB
    float* col_part = row_part + (size_t)NCH * ntok * TABLE;       // 12.6 MB
    float* per_tok  = col_part + (size_t)NCH * ntok * TABLE;       // 8 KB

    const int ntiles = (ntok + KTOK - 1) / KTOK;       // 171
    const int nblk   = 256 * NCH * 2 + ntiles * NCH * 2;  // 3072 + 2052 = 5124

    k_ztrans <<<DIM, 256, 0, stream>>>(Wrow, WrowT, counts);
    k_bucket <<<(ntok + 255) / 256, 256, 0, stream>>>(tgt, ntok, counts, bucket);
    k_stream <<<nblk, 64, 0, stream>>>(hs, WrowT, CW, counts, bucket,
                                       row_part, col_part, ntok);
    k_nll2   <<<(ntok + 3) / 4, 256, 0, stream>>>(row_part, col_part, brow, cbias,
                                                  tgt, ntok, per_tok);
    k_reduce <<<1, 256, 0, stream>>>(per_tok, ntok, out);
}